// Round 8
// baseline (299.591 us; speedup 1.0000x reference)
//
#include <hip/hip_runtime.h>

// AWQ int4 GEMM: out[M,N] = x[M,K] @ dequant(qweight,qzeros,scales)
// M=2048 K=4096 N=11008 G=128.
// TWO-PASS + fine-phase GEMM:
//  (1) xconv: x fp32 -> f16 pre-swizzled [r][s'] K32-tile images
//  (2) wdeq : W int4 -> f16 dequant ONCE into pre-swizzled K32-tile images
//  (3) awq_gemm4: 256x256 tile, BK=32, 8 waves (2Mx4N, per-wave 128x64),
//      ring-4 LDS buffers (128KB), vmcnt(8) counted at every tile boundary,
//      2 phases/tile {ds_read || gload_lds -> barrier -> 16 MFMA setprio}.

#define MDIM 2048
#define KDIM 4096
#define NDIM 11008
#define NPC  1376
#define NT2  128            // K / 32
#define NBB  43             // N / 256
#define MBB  8              // M / 256

typedef _Float16 half8   __attribute__((ext_vector_type(8)));
typedef _Float16 half2v  __attribute__((ext_vector_type(2)));
typedef __fp16   fp16x2n __attribute__((ext_vector_type(2)));
typedef float    f32x4   __attribute__((ext_vector_type(4)));

__device__ __forceinline__ half2v u2h(unsigned u) { union { unsigned u; half2v h; } v; v.u = u; return v.h; }
__device__ __forceinline__ unsigned h2u(half2v h) { union { unsigned u; half2v h; } v; v.h = h; return v.u; }
__device__ __forceinline__ unsigned pkrtz(float a, float b) {
    union { fp16x2n h; unsigned u; } v;
    v.h = __builtin_amdgcn_cvt_pkrtz(a, b);
    return v.u;
}

// ============ pass 1: x fp32 -> f16 K32-tile images ============
// image per (mbb 0..7, tt 0..127): [r 0..255][s' = s^((r>>1)&3)][8 half] = 16KB
__global__ __launch_bounds__(256) void xconv(const float* __restrict__ x,
                                             _Float16* __restrict__ xi) {
    const int id  = blockIdx.x * 256 + threadIdx.x;   // 2^20
    const int s   = id & 3;
    const int r   = (id >> 2) & 255;
    const int tt  = (id >> 10) & 127;
    const int mbb = id >> 17;
    const float* src = x + (size_t)(mbb * 256 + r) * KDIM + tt * 32 + s * 8;
    const float4 f0 = *(const float4*)src;
    const float4 f1 = *(const float4*)(src + 4);
    uint4 w;
    w.x = pkrtz(f0.x, f0.y); w.y = pkrtz(f0.z, f0.w);
    w.z = pkrtz(f1.x, f1.y); w.w = pkrtz(f1.z, f1.w);
    const size_t off = (size_t)(mbb * NT2 + tt) * 8192 + r * 32
                     + (size_t)((s ^ ((r >> 1) & 3)) * 8);
    *(uint4*)(xi + off) = w;
}

// ============ pass 2: W dequant ONCE -> f16 K32-tile images ============
// image per (nbb 0..42, tt 0..127): [n 0..255][s' = s^((n>>1)&3)][8 half] = 16KB
// block = (nbb, by): 256 n x 64 k -> 2 images via LDS, coalesced copy-out.
__global__ __launch_bounds__(256)
void wdeq(const int* __restrict__ qw, const unsigned* __restrict__ qz,
          const float* __restrict__ sc, _Float16* __restrict__ wi)
{
    __shared__ _Float16 img[2 * 8192];   // 32KB

    const int t   = threadIdx.x;
    const int pc5 = t & 31;              // packed col within nbb (32 pcs = 256 n)
    const int ko  = t >> 5;              // k-octet within 64 (0..7)
    const int nbb = blockIdx.x;          // 0..42
    const int by  = blockIdx.y;          // 0..63
    const int g   = by >> 1;             // quant group
    const int pcg = nbb * 32 + pc5;
    const int s   = ko & 3;              // k-slot within K32 tile
    const int li  = ko >> 2;             // which of the 2 images

    const int* qp = qw + (size_t)(by * 64 + ko * 8) * NPC + pcg;
    unsigned w[8];
    #pragma unroll
    for (int r = 0; r < 8; ++r) w[r] = (unsigned)qp[(size_t)r * NPC];
    const unsigned rz = qz[(size_t)g * NPC + pcg];
    const float* sp = sc + (size_t)g * NDIM + nbb * 256 + pc5 * 8;
    const float4 rs0 = *(const float4*)sp;
    const float4 rs1 = *(const float4*)(sp + 4);

    const unsigned M_ = 0x000F000Fu, G_ = 0x64006400u;

    #pragma unroll
    for (int pp = 0; pp < 4; ++pp) {
        const int p = (pp + pc5) & 3;    // lane-staggered to spread LDS banks
        const unsigned zp  = ((rz >> (4 * p)) & M_) | G_;
        const unsigned spk = (p == 0) ? pkrtz(rs0.x, rs0.y)
                           : (p == 1) ? pkrtz(rs0.z, rs0.w)
                           : (p == 2) ? pkrtz(rs1.x, rs1.y)
                                      : pkrtz(rs1.z, rs1.w);
        unsigned d[8];
        #pragma unroll
        for (int r = 0; r < 8; ++r)
            d[r] = h2u((u2h(((w[r] >> (4 * p)) & M_) | G_) - u2h(zp)) * u2h(spk));
        uint4 ev, od;
        ev.x = __builtin_amdgcn_perm(d[1], d[0], 0x05040100u);
        ev.y = __builtin_amdgcn_perm(d[3], d[2], 0x05040100u);
        ev.z = __builtin_amdgcn_perm(d[5], d[4], 0x05040100u);
        ev.w = __builtin_amdgcn_perm(d[7], d[6], 0x05040100u);
        od.x = __builtin_amdgcn_perm(d[1], d[0], 0x07060302u);
        od.y = __builtin_amdgcn_perm(d[3], d[2], 0x07060302u);
        od.z = __builtin_amdgcn_perm(d[5], d[4], 0x07060302u);
        od.w = __builtin_amdgcn_perm(d[7], d[6], 0x07060302u);
        const int ne = pc5 * 8 + 2 * p, no = ne + 1;
        *(uint4*)(img + li * 8192 + ne * 32 + ((s ^ ((ne >> 1) & 3)) * 8)) = ev;
        *(uint4*)(img + li * 8192 + no * 32 + ((s ^ ((no >> 1) & 3)) * 8)) = od;
    }
    __syncthreads();

    _Float16* dst = wi + (size_t)(nbb * NT2 + by * 2) * 8192;
    #pragma unroll
    for (int i = 0; i < 8; ++i) {
        const int idx = i * 256 + t;
        *(uint4*)(dst + idx * 8) = *(const uint4*)(img + idx * 8);
    }
}

// ============ pass 3: ring-4 counted-vmcnt fine-phase GEMM ============
__global__ __launch_bounds__(512, 2)
void awq_gemm4(const _Float16* __restrict__ xi,
               const _Float16* __restrict__ wi,
               float* __restrict__ out)
{
    __shared__ _Float16 As[4][8192];   // 64KB: ring of 4 K32-tiles (A)
    __shared__ _Float16 Bs[4][8192];   // 64KB: ring of 4 K32-tiles (B)

    const int t    = threadIdx.x;
    const int lane = t & 63;
    const int wid  = t >> 6;
    const int WR   = wid >> 2;         // 0..1 : 128-row band
    const int WC   = wid & 3;          // 0..3 : 64-col band
    const int l15  = lane & 15;
    // swizzled slot offset (f16 units) — uniform for all this thread's reads
    const int soff = ((lane >> 4) ^ ((l15 >> 1) & 3)) * 8;
    const int arow0 = WR * 128 + l15;
    const int brow0 = WC * 64 + l15;

    // bijective XCD swizzle (344 = 8*43): XCD x gets contiguous 43-chunk of W;
    // consecutive W share nbb -> B panel (2MB) stays L2-resident per XCD.
    const int bid = blockIdx.x;
    const int W   = (bid & 7) * NBB + (bid >> 3);
    const int nbb = W >> 3;
    const int mbb = W & 7;

    const _Float16* aimg = xi + (size_t)mbb * NT2 * 8192;
    const _Float16* bimg = wi + (size_t)nbb * NT2 * 8192;

    f32x4 acc[8][4];
    #pragma unroll
    for (int i = 0; i < 8; ++i)
        #pragma unroll
        for (int j = 0; j < 4; ++j)
            acc[i][j] = (f32x4){0.f, 0.f, 0.f, 0.f};

#define GLL(SRC, DST) __builtin_amdgcn_global_load_lds(                        \
    (const __attribute__((address_space(1))) void*)(SRC),                     \
    (__attribute__((address_space(3))) void*)(DST), 16, 0, 0)

#define ISSUE_A(PT) do {                                                      \
    const _Float16* s_ = aimg + (size_t)(PT) * 8192 + t * 8;                  \
    _Float16* d_ = &As[(PT) & 3][t * 8];                                      \
    GLL(s_, d_); GLL(s_ + 4096, d_ + 4096);                                   \
} while (0)

#define ISSUE_B(PT) do {                                                      \
    const _Float16* s_ = bimg + (size_t)(PT) * 8192 + t * 8;                  \
    _Float16* d_ = &Bs[(PT) & 3][t * 8];                                      \
    GLL(s_, d_); GLL(s_ + 4096, d_ + 4096);                                   \
} while (0)

#define RD_A(AB, MH, I) (*(const half8*)((AB) + (arow0 + (MH)*64 + (I)*16) * 32 + soff))
#define RD_B(BB, J)     (*(const half8*)((BB) + (brow0 + (J)*16) * 32 + soff))

#define MF4(I, AV)                                                            \
    acc[I][0] = __builtin_amdgcn_mfma_f32_16x16x32_f16(AV, bf0, acc[I][0], 0, 0, 0); \
    acc[I][1] = __builtin_amdgcn_mfma_f32_16x16x32_f16(AV, bf1, acc[I][1], 0, 0, 0); \
    acc[I][2] = __builtin_amdgcn_mfma_f32_16x16x32_f16(AV, bf2, acc[I][2], 0, 0, 0); \
    acc[I][3] = __builtin_amdgcn_mfma_f32_16x16x32_f16(AV, bf3, acc[I][3], 0, 0, 0)

#define TILE(TT, DOISSUE, VMSTR) do {                                         \
    asm volatile("s_waitcnt vmcnt(" VMSTR ")" ::: "memory");                  \
    __builtin_amdgcn_sched_barrier(0);                                        \
    __builtin_amdgcn_s_barrier();                                             \
    __builtin_amdgcn_sched_barrier(0);                                        \
    const _Float16* Ab = As[(TT) & 3];                                        \
    const _Float16* Bb = Bs[(TT) & 3];                                        \
    half8 bf0 = RD_B(Bb, 0), bf1 = RD_B(Bb, 1);                               \
    half8 bf2 = RD_B(Bb, 2), bf3 = RD_B(Bb, 3);                               \
    {   /* phase 1: m-half 0 */                                               \
        half8 a0 = RD_A(Ab, 0, 0), a1 = RD_A(Ab, 0, 1);                       \
        half8 a2 = RD_A(Ab, 0, 2), a3 = RD_A(Ab, 0, 3);                       \
        if (DOISSUE) ISSUE_A((TT) + 3);                                       \
        __builtin_amdgcn_sched_barrier(0);                                    \
        __builtin_amdgcn_s_setprio(1);                                        \
        MF4(0, a0); MF4(1, a1); MF4(2, a2); MF4(3, a3);                       \
        __builtin_amdgcn_s_setprio(0);                                        \
    }                                                                         \
    __builtin_amdgcn_sched_barrier(0);                                        \
    __builtin_amdgcn_s_barrier();                                             \
    __builtin_amdgcn_sched_barrier(0);                                        \
    {   /* phase 2: m-half 1 (reuse bf0..3) */                                \
        half8 a4 = RD_A(Ab, 1, 0), a5 = RD_A(Ab, 1, 1);                       \
        half8 a6 = RD_A(Ab, 1, 2), a7 = RD_A(Ab, 1, 3);                       \
        if (DOISSUE) ISSUE_B((TT) + 3);                                       \
        __builtin_amdgcn_sched_barrier(0);                                    \
        __builtin_amdgcn_s_setprio(1);                                        \
        MF4(4, a4); MF4(5, a5); MF4(6, a6); MF4(7, a7);                       \
        __builtin_amdgcn_s_setprio(0);                                        \
    }                                                                         \
} while (0)

    // prologue: 3 K-tiles in flight (12 loads/thread)
    ISSUE_A(0); ISSUE_B(0);
    ISSUE_A(1); ISSUE_B(1);
    ISSUE_A(2); ISSUE_B(2);

    for (int tt = 0; tt < NT2 - 3; ++tt) {
        TILE(tt, 1, "8");          // steady: wait own tile, 8 newer in flight
    }
    TILE(NT2 - 3, 0, "8");
    TILE(NT2 - 2, 0, "4");
    TILE(NT2 - 1, 0, "0");

    // epilogue: C/D layout col=lane&15, row=(lane>>4)*4+e
    const int m0 = mbb * 256, n0 = nbb * 256;
    const int crow = (lane >> 4) * 4;
    #pragma unroll
    for (int i = 0; i < 8; ++i) {
        #pragma unroll
        for (int j = 0; j < 4; ++j) {
            const size_t base =
                (size_t)(m0 + WR * 128 + i * 16 + crow) * NDIM +
                (n0 + WC * 64 + j * 16 + l15);
            #pragma unroll
            for (int e = 0; e < 4; ++e)
                out[base + (size_t)e * NDIM] = acc[i][j][e];
        }
    }
#undef GLL
#undef ISSUE_A
#undef ISSUE_B
#undef RD_A
#undef RD_B
#undef MF4
#undef TILE
}

extern "C" void kernel_launch(void* const* d_in, const int* in_sizes, int n_in,
                              void* d_out, int out_size, void* d_ws, size_t ws_size,
                              hipStream_t stream) {
    const float*    x  = (const float*)d_in[0];
    const int*      qw = (const int*)d_in[1];
    const unsigned* qz = (const unsigned*)d_in[2];
    const float*    sc = (const float*)d_in[3];
    float* out = (float*)d_out;

    const size_t XI = (size_t)MDIM * KDIM * 2;            // 16.8 MB
    const size_t WI = (size_t)NBB * NT2 * 16384;          // 90.2 MB
    if (ws_size < XI + WI) return;                        // ws proven sufficient

    _Float16* xi = (_Float16*)d_ws;
    _Float16* wi = (_Float16*)((char*)d_ws + XI);

    xconv<<<4096, 256, 0, stream>>>(x, xi);
    wdeq<<<dim3(NBB, 64), 256, 0, stream>>>(qw, qz, sc, wi);
    awq_gemm4<<<MBB * NBB, 512, 0, stream>>>(xi, wi, out);
}

// Round 9
// 240.359 us; speedup vs baseline: 1.2464x; 1.2464x over previous
//
#include <hip/hip_runtime.h>

// AWQ int4 GEMM: out[M,N] = x[M,K] @ dequant(qweight,qzeros,scales)
// M=2048 K=4096 N=11008 G=128.
// TWO-PASS + high-occupancy simple-dbuf GEMM:
//  (1) xconv: x fp32 -> f16 conflict-free K32-tile images (8KB each)
//  (2) wdeq : W int4 -> f16 dequant ONCE into K32-tile images
//  (3) awq_gemm5: 128x128 tile, BK=32, 4 waves, dbuf 32KB LDS -> 4 blocks/CU,
//      one __syncthreads per K32 tile (R6-proven loop), 0-conflict swizzle.

#define MDIM 2048
#define KDIM 4096
#define NDIM 11008
#define NPC  1376
#define NT2  128            // K/32 tiles
#define TSZ  4096           // halves per K32 image: [128 rows][4 slots][8 halves]

typedef _Float16 half8   __attribute__((ext_vector_type(8)));
typedef _Float16 half2v  __attribute__((ext_vector_type(2)));
typedef __fp16   fp16x2n __attribute__((ext_vector_type(2)));
typedef float    f32x4   __attribute__((ext_vector_type(4)));

__device__ __forceinline__ half2v u2h(unsigned u) { union { unsigned u; half2v h; } v; v.u = u; return v.h; }
__device__ __forceinline__ unsigned h2u(half2v h) { union { unsigned u; half2v h; } v; v.h = h; return v.u; }
__device__ __forceinline__ unsigned pkrtz(float a, float b) {
    union { fp16x2n h; unsigned u; } v;
    v.h = __builtin_amdgcn_cvt_pkrtz(a, b);
    return v.u;
}

// ============ pass 1: x fp32 -> f16 K32-tile images ============
// image per (mb 0..15, tt 0..127): [r 0..127][s' = s^((r>>1)&3)][8 half] = 8KB
__global__ __launch_bounds__(256) void xconv(const float* __restrict__ x,
                                             _Float16* __restrict__ xi) {
    const int id = blockIdx.x * 256 + threadIdx.x;   // 2^20
    const int s  = id & 3;
    const int r  = (id >> 2) & 127;
    const int tt = (id >> 9) & 127;
    const int mb = id >> 16;
    const float* src = x + (size_t)(mb * 128 + r) * KDIM + tt * 32 + s * 8;
    const float4 f0 = *(const float4*)src;
    const float4 f1 = *(const float4*)(src + 4);
    uint4 w;
    w.x = pkrtz(f0.x, f0.y); w.y = pkrtz(f0.z, f0.w);
    w.z = pkrtz(f1.x, f1.y); w.w = pkrtz(f1.z, f1.w);
    const size_t off = (size_t)(mb * NT2 + tt) * TSZ + r * 32
                     + (size_t)((s ^ ((r >> 1) & 3)) * 8);
    *(uint4*)(xi + off) = w;
}

// ============ pass 2: W dequant ONCE -> f16 K32-tile images ============
// image per (nb 0..85, tt 0..127): [n 0..127][s' = s^((n>>1)&3)][8 half] = 8KB
// block (nb, by): 128 n x 128 k (= quant group by) -> 4 images via LDS.
__global__ __launch_bounds__(256)
void wdeq(const int* __restrict__ qw, const unsigned* __restrict__ qz,
          const float* __restrict__ sc, _Float16* __restrict__ wi)
{
    __shared__ _Float16 img[4 * TSZ];    // 32KB = 4 images

    const int t   = threadIdx.x;
    const int pc4 = t & 15;              // packed col within nb (16 pcs = 128 n)
    const int ko  = t >> 4;              // k-octet within 128 (0..15)
    const int nb  = blockIdx.x;          // 0..85
    const int by  = blockIdx.y;          // 0..31 == quant group
    const int pcg = nb * 16 + pc4;
    const int s   = ko & 3;              // k-slot within K32 tile
    const int li  = ko >> 2;             // which of the 4 images

    const int* qp = qw + (size_t)(by * 128 + ko * 8) * NPC + pcg;
    unsigned w[8];
    #pragma unroll
    for (int r = 0; r < 8; ++r) w[r] = (unsigned)qp[(size_t)r * NPC];
    const unsigned rz = qz[(size_t)by * NPC + pcg];
    const float* sp = sc + (size_t)by * NDIM + nb * 128 + pc4 * 8;
    const float4 rs0 = *(const float4*)sp;
    const float4 rs1 = *(const float4*)(sp + 4);

    const unsigned M_ = 0x000F000Fu, G_ = 0x64006400u;

    #pragma unroll
    for (int pp = 0; pp < 4; ++pp) {
        const int p = (pp + pc4) & 3;    // lane-staggered LDS write banks
        const unsigned zp  = ((rz >> (4 * p)) & M_) | G_;
        const unsigned spk = (p == 0) ? pkrtz(rs0.x, rs0.y)
                           : (p == 1) ? pkrtz(rs0.z, rs0.w)
                           : (p == 2) ? pkrtz(rs1.x, rs1.y)
                                      : pkrtz(rs1.z, rs1.w);
        unsigned d[8];
        #pragma unroll
        for (int r = 0; r < 8; ++r)
            d[r] = h2u((u2h(((w[r] >> (4 * p)) & M_) | G_) - u2h(zp)) * u2h(spk));
        uint4 ev, od;
        ev.x = __builtin_amdgcn_perm(d[1], d[0], 0x05040100u);
        ev.y = __builtin_amdgcn_perm(d[3], d[2], 0x05040100u);
        ev.z = __builtin_amdgcn_perm(d[5], d[4], 0x05040100u);
        ev.w = __builtin_amdgcn_perm(d[7], d[6], 0x05040100u);
        od.x = __builtin_amdgcn_perm(d[1], d[0], 0x07060302u);
        od.y = __builtin_amdgcn_perm(d[3], d[2], 0x07060302u);
        od.z = __builtin_amdgcn_perm(d[5], d[4], 0x07060302u);
        od.w = __builtin_amdgcn_perm(d[7], d[6], 0x07060302u);
        const int ne = pc4 * 8 + 2 * p, no = ne + 1;
        *(uint4*)(img + li * TSZ + ne * 32 + ((s ^ ((ne >> 1) & 3)) * 8)) = ev;
        *(uint4*)(img + li * TSZ + no * 32 + ((s ^ ((no >> 1) & 3)) * 8)) = od;
    }
    __syncthreads();

    _Float16* dst = wi + (size_t)(nb * NT2 + by * 4) * TSZ;
    #pragma unroll
    for (int i = 0; i < 8; ++i) {
        const int idx = i * 256 + t;
        *(uint4*)(dst + idx * 8) = *(const uint4*)(img + idx * 8);
    }
}

// ============ pass 3: 4-blocks/CU simple-dbuf GEMM ============
__global__ __launch_bounds__(256, 4)
void awq_gemm5(const _Float16* __restrict__ xi,
               const _Float16* __restrict__ wi,
               float* __restrict__ out)
{
    __shared__ _Float16 As[2][TSZ];   // 8KB each
    __shared__ _Float16 Bs[2][TSZ];   // total 32KB -> 4 blocks/CU

    const int t    = threadIdx.x;
    const int lane = t & 63;
    const int wave = t >> 6;           // 0..3
    const int WR   = wave >> 1;        // 0..1
    const int WC   = wave & 1;         // 0..1
    const int l15  = lane & 15;
    // conflict-free swizzled slot offset (halves), uniform per thread
    const int soff = ((lane >> 4) ^ ((l15 >> 1) & 3)) * 8;

    const int mb = blockIdx.x;         // 0..15 (fast: share B panel)
    const int nb = blockIdx.y;         // 0..85

    const _Float16* aimg = xi + (size_t)mb * NT2 * TSZ + t * 8;
    const _Float16* bimg = wi + (size_t)nb * NT2 * TSZ + t * 8;

    f32x4 acc[4][4];
    #pragma unroll
    for (int i = 0; i < 4; ++i)
        #pragma unroll
        for (int j = 0; j < 4; ++j)
            acc[i][j] = (f32x4){0.f, 0.f, 0.f, 0.f};

#define GLL(SRC, DST) __builtin_amdgcn_global_load_lds(                        \
    (const __attribute__((address_space(1))) void*)(SRC),                     \
    (__attribute__((address_space(3))) void*)(DST), 16, 0, 0)

#define ISSUE(TT, B_) do {                                                    \
    const _Float16* a_ = aimg + (size_t)(TT) * TSZ;                           \
    const _Float16* b_ = bimg + (size_t)(TT) * TSZ;                           \
    GLL(a_,        &As[B_][t * 8]);                                           \
    GLL(a_ + 2048, &As[B_][2048 + t * 8]);                                    \
    GLL(b_,        &Bs[B_][t * 8]);                                           \
    GLL(b_ + 2048, &Bs[B_][2048 + t * 8]);                                    \
} while (0)

#define COMPUTE(B_) do {                                                      \
    half8 bf[4];                                                              \
    _Pragma("unroll")                                                         \
    for (int j = 0; j < 4; ++j)                                               \
        bf[j] = *(const half8*)&Bs[B_][(WC * 64 + j * 16 + l15) * 32 + soff]; \
    _Pragma("unroll")                                                         \
    for (int i = 0; i < 4; ++i) {                                             \
        const half8 af = *(const half8*)&As[B_][(WR * 64 + i * 16 + l15) * 32 + soff]; \
        _Pragma("unroll")                                                     \
        for (int j = 0; j < 4; ++j)                                           \
            acc[i][j] = __builtin_amdgcn_mfma_f32_16x16x32_f16(               \
                af, bf[j], acc[i][j], 0, 0, 0);                               \
    }                                                                         \
} while (0)

    ISSUE(0, 0);
    __syncthreads();                   // tile 0 resident

    int cur = 0;
    for (int tt = 0; tt < NT2; ++tt) {
        if (tt + 1 < NT2) ISSUE(tt + 1, cur ^ 1);   // prefetch before compute
        COMPUTE(cur);
        __syncthreads();               // drain prefetch + publish
        cur ^= 1;
    }

    // epilogue: C/D layout col=lane&15, row=(lane>>4)*4+e
    const int m0 = mb * 128, n0 = nb * 128;
    const int crow = (lane >> 4) * 4;
    #pragma unroll
    for (int i = 0; i < 4; ++i) {
        #pragma unroll
        for (int j = 0; j < 4; ++j) {
            const size_t base =
                (size_t)(m0 + WR * 64 + i * 16 + crow) * NDIM +
                (n0 + WC * 64 + j * 16 + l15);
            #pragma unroll
            for (int e = 0; e < 4; ++e)
                out[base + (size_t)e * NDIM] = acc[i][j][e];
        }
    }
#undef GLL
#undef ISSUE
#undef COMPUTE
}

extern "C" void kernel_launch(void* const* d_in, const int* in_sizes, int n_in,
                              void* d_out, int out_size, void* d_ws, size_t ws_size,
                              hipStream_t stream) {
    const float*    x  = (const float*)d_in[0];
    const int*      qw = (const int*)d_in[1];
    const unsigned* qz = (const unsigned*)d_in[2];
    const float*    sc = (const float*)d_in[3];
    float* out = (float*)d_out;

    const size_t XI = (size_t)MDIM * KDIM * 2;            // 16.8 MB
    const size_t WI = (size_t)86 * NT2 * TSZ * 2;         // 90.2 MB
    if (ws_size < XI + WI) return;                        // ws proven sufficient

    _Float16* xi = (_Float16*)d_ws;
    _Float16* wi = (_Float16*)((char*)d_ws + XI);

    xconv<<<4096, 256, 0, stream>>>(x, xi);
    wdeq<<<dim3(86, 32), 256, 0, stream>>>(qw, qz, sc, wi);
    awq_gemm5<<<dim3(16, 86), 256, 0, stream>>>(xi, wi, out);
}

// Round 10
// 225.455 us; speedup vs baseline: 1.3288x; 1.0661x over previous
//
#include <hip/hip_runtime.h>

// AWQ int4 GEMM: out[M,N] = x[M,K] @ dequant(qweight,qzeros,scales)
// M=2048 K=4096 N=11008 G=128.
// TWO-PASS + high-intensity dbuf GEMM:
//  (1) xconv: x fp32 -> f16 conflict-free K32-tile images (256-row, 16KB)
//  (2) wdeq : W int4 -> f16 dequant ONCE into K32-tile images (128-row, 8KB)
//  (3) awq_gemm6: 256x128 block, 4 waves, per-wave 128x64 (43.7 FLOP/LDS-byte),
//      BK=32, dbuf 48KB, 2 blocks/CU, one __syncthreads per tile (R9-proven).

#define MDIM 2048
#define KDIM 4096
#define NDIM 11008
#define NPC  1376
#define NT2  128            // K/32 tiles
#define ATSZ 8192           // halves per A K32 image: [256 r][4 s'][8]
#define BTSZ 4096           // halves per B K32 image: [128 n][4 s'][8]

typedef _Float16 half8   __attribute__((ext_vector_type(8)));
typedef _Float16 half2v  __attribute__((ext_vector_type(2)));
typedef __fp16   fp16x2n __attribute__((ext_vector_type(2)));
typedef float    f32x4   __attribute__((ext_vector_type(4)));

__device__ __forceinline__ half2v u2h(unsigned u) { union { unsigned u; half2v h; } v; v.u = u; return v.h; }
__device__ __forceinline__ unsigned h2u(half2v h) { union { unsigned u; half2v h; } v; v.h = h; return v.u; }
__device__ __forceinline__ unsigned pkrtz(float a, float b) {
    union { fp16x2n h; unsigned u; } v;
    v.h = __builtin_amdgcn_cvt_pkrtz(a, b);
    return v.u;
}

// ============ pass 1: x fp32 -> f16 K32-tile images (256-row) ============
// image per (mb 0..7, tt 0..127): [r 0..255][s' = s^((r>>1)&3)][8 half] = 16KB
__global__ __launch_bounds__(256) void xconv(const float* __restrict__ x,
                                             _Float16* __restrict__ xi) {
    const int id = blockIdx.x * 256 + threadIdx.x;   // 2^20
    const int s  = id & 3;
    const int r  = (id >> 2) & 255;
    const int tt = (id >> 10) & 127;
    const int mb = id >> 17;                         // 0..7
    const float* src = x + (size_t)(mb * 256 + r) * KDIM + tt * 32 + s * 8;
    const float4 f0 = *(const float4*)src;
    const float4 f1 = *(const float4*)(src + 4);
    uint4 w;
    w.x = pkrtz(f0.x, f0.y); w.y = pkrtz(f0.z, f0.w);
    w.z = pkrtz(f1.x, f1.y); w.w = pkrtz(f1.z, f1.w);
    const size_t off = (size_t)(mb * NT2 + tt) * ATSZ + r * 32
                     + (size_t)((s ^ ((r >> 1) & 3)) * 8);
    *(uint4*)(xi + off) = w;
}

// ============ pass 2: W dequant ONCE -> f16 K32-tile images ============
// image per (nb 0..85, tt 0..127): [n 0..127][s' = s^((n>>1)&3)][8 half] = 8KB
__global__ __launch_bounds__(256)
void wdeq(const int* __restrict__ qw, const unsigned* __restrict__ qz,
          const float* __restrict__ sc, _Float16* __restrict__ wi)
{
    __shared__ _Float16 img[4 * BTSZ];   // 32KB = 4 images

    const int t   = threadIdx.x;
    const int pc4 = t & 15;              // packed col within nb (16 pcs = 128 n)
    const int ko  = t >> 4;              // k-octet within 128 (0..15)
    const int nb  = blockIdx.x;          // 0..85
    const int by  = blockIdx.y;          // 0..31 == quant group
    const int pcg = nb * 16 + pc4;
    const int s   = ko & 3;              // k-slot within K32 tile
    const int li  = ko >> 2;             // which of the 4 images

    const int* qp = qw + (size_t)(by * 128 + ko * 8) * NPC + pcg;
    unsigned w[8];
    #pragma unroll
    for (int r = 0; r < 8; ++r) w[r] = (unsigned)qp[(size_t)r * NPC];
    const unsigned rz = qz[(size_t)by * NPC + pcg];
    const float* sp = sc + (size_t)by * NDIM + nb * 128 + pc4 * 8;
    const float4 rs0 = *(const float4*)sp;
    const float4 rs1 = *(const float4*)(sp + 4);

    const unsigned M_ = 0x000F000Fu, G_ = 0x64006400u;

    #pragma unroll
    for (int pp = 0; pp < 4; ++pp) {
        const int p = (pp + pc4) & 3;    // lane-staggered LDS write banks
        const unsigned zp  = ((rz >> (4 * p)) & M_) | G_;
        const unsigned spk = (p == 0) ? pkrtz(rs0.x, rs0.y)
                           : (p == 1) ? pkrtz(rs0.z, rs0.w)
                           : (p == 2) ? pkrtz(rs1.x, rs1.y)
                                      : pkrtz(rs1.z, rs1.w);
        unsigned d[8];
        #pragma unroll
        for (int r = 0; r < 8; ++r)
            d[r] = h2u((u2h(((w[r] >> (4 * p)) & M_) | G_) - u2h(zp)) * u2h(spk));
        uint4 ev, od;
        ev.x = __builtin_amdgcn_perm(d[1], d[0], 0x05040100u);
        ev.y = __builtin_amdgcn_perm(d[3], d[2], 0x05040100u);
        ev.z = __builtin_amdgcn_perm(d[5], d[4], 0x05040100u);
        ev.w = __builtin_amdgcn_perm(d[7], d[6], 0x05040100u);
        od.x = __builtin_amdgcn_perm(d[1], d[0], 0x07060302u);
        od.y = __builtin_amdgcn_perm(d[3], d[2], 0x07060302u);
        od.z = __builtin_amdgcn_perm(d[5], d[4], 0x07060302u);
        od.w = __builtin_amdgcn_perm(d[7], d[6], 0x07060302u);
        const int ne = pc4 * 8 + 2 * p, no = ne + 1;
        *(uint4*)(img + li * BTSZ + ne * 32 + ((s ^ ((ne >> 1) & 3)) * 8)) = ev;
        *(uint4*)(img + li * BTSZ + no * 32 + ((s ^ ((no >> 1) & 3)) * 8)) = od;
    }
    __syncthreads();

    _Float16* dst = wi + (size_t)(nb * NT2 + by * 4) * BTSZ;
    #pragma unroll
    for (int i = 0; i < 8; ++i) {
        const int idx = i * 256 + t;
        *(uint4*)(dst + idx * 8) = *(const uint4*)(img + idx * 8);
    }
}

// ============ pass 3: per-wave 128x64, 2 blocks/CU dbuf GEMM ============
__global__ __launch_bounds__(256, 2)
void awq_gemm6(const _Float16* __restrict__ xi,
               const _Float16* __restrict__ wi,
               float* __restrict__ out)
{
    __shared__ _Float16 As[2][ATSZ];   // 16KB each
    __shared__ _Float16 Bs[2][BTSZ];   // 8KB each; total 48KB -> 2 blocks/CU

    const int t    = threadIdx.x;
    const int lane = t & 63;
    const int wave = t >> 6;           // 0..3
    const int WR   = wave >> 1;        // 0..1 : 128-row band
    const int WC   = wave & 1;         // 0..1 : 64-col band
    const int l15  = lane & 15;
    // conflict-free swizzled slot offset (halves), uniform per thread
    const int soff = ((lane >> 4) ^ ((l15 >> 1) & 3)) * 8;

    const int mb = blockIdx.x;         // 0..7  (fast axis -> XCD == mb)
    const int nb = blockIdx.y;         // 0..85

    const _Float16* aimg = xi + (size_t)mb * NT2 * ATSZ + t * 8;
    const _Float16* bimg = wi + (size_t)nb * NT2 * BTSZ + t * 8;

    f32x4 acc[8][4];
    #pragma unroll
    for (int i = 0; i < 8; ++i)
        #pragma unroll
        for (int j = 0; j < 4; ++j)
            acc[i][j] = (f32x4){0.f, 0.f, 0.f, 0.f};

#define GLL(SRC, DST) __builtin_amdgcn_global_load_lds(                        \
    (const __attribute__((address_space(1))) void*)(SRC),                     \
    (__attribute__((address_space(3))) void*)(DST), 16, 0, 0)

#define ISSUE(TT, B_) do {                                                    \
    const _Float16* a_ = aimg + (size_t)(TT) * ATSZ;                          \
    const _Float16* b_ = bimg + (size_t)(TT) * BTSZ;                          \
    GLL(a_,        &As[B_][t * 8]);                                           \
    GLL(a_ + 2048, &As[B_][2048 + t * 8]);                                    \
    GLL(a_ + 4096, &As[B_][4096 + t * 8]);                                    \
    GLL(a_ + 6144, &As[B_][6144 + t * 8]);                                    \
    GLL(b_,        &Bs[B_][t * 8]);                                           \
    GLL(b_ + 2048, &Bs[B_][2048 + t * 8]);                                    \
} while (0)

#define COMPUTE(B_) do {                                                      \
    half8 bf[4];                                                              \
    _Pragma("unroll")                                                         \
    for (int j = 0; j < 4; ++j)                                               \
        bf[j] = *(const half8*)&Bs[B_][(WC * 64 + j * 16 + l15) * 32 + soff]; \
    _Pragma("unroll")                                                         \
    for (int i = 0; i < 8; ++i) {                                             \
        const half8 af = *(const half8*)&As[B_][(WR * 128 + i * 16 + l15) * 32 + soff]; \
        _Pragma("unroll")                                                     \
        for (int j = 0; j < 4; ++j)                                           \
            acc[i][j] = __builtin_amdgcn_mfma_f32_16x16x32_f16(               \
                af, bf[j], acc[i][j], 0, 0, 0);                               \
    }                                                                         \
} while (0)

    ISSUE(0, 0);
    __syncthreads();                   // tile 0 resident

    int cur = 0;
    for (int tt = 0; tt < NT2; ++tt) {
        if (tt + 1 < NT2) ISSUE(tt + 1, cur ^ 1);   // prefetch before compute
        COMPUTE(cur);
        __syncthreads();               // drain prefetch + publish
        cur ^= 1;
    }

    // epilogue: C/D layout col=lane&15, row=(lane>>4)*4+e
    const int m0 = mb * 256, n0 = nb * 128;
    const int crow = (lane >> 4) * 4;
    #pragma unroll
    for (int i = 0; i < 8; ++i) {
        #pragma unroll
        for (int j = 0; j < 4; ++j) {
            const size_t base =
                (size_t)(m0 + WR * 128 + i * 16 + crow) * NDIM +
                (n0 + WC * 64 + j * 16 + l15);
            #pragma unroll
            for (int e = 0; e < 4; ++e)
                out[base + (size_t)e * NDIM] = acc[i][j][e];
        }
    }
#undef GLL
#undef ISSUE
#undef COMPUTE
}

extern "C" void kernel_launch(void* const* d_in, const int* in_sizes, int n_in,
                              void* d_out, int out_size, void* d_ws, size_t ws_size,
                              hipStream_t stream) {
    const float*    x  = (const float*)d_in[0];
    const int*      qw = (const int*)d_in[1];
    const unsigned* qz = (const unsigned*)d_in[2];
    const float*    sc = (const float*)d_in[3];
    float* out = (float*)d_out;

    const size_t XI = (size_t)MDIM * KDIM * 2;            // 16.8 MB
    const size_t WI = (size_t)86 * NT2 * BTSZ * 2;        // 90.2 MB
    if (ws_size < XI + WI) return;                        // ws proven sufficient

    _Float16* xi = (_Float16*)d_ws;
    _Float16* wi = (_Float16*)((char*)d_ws + XI);

    xconv<<<4096, 256, 0, stream>>>(x, xi);
    wdeq<<<dim3(86, 32), 256, 0, stream>>>(qw, qz, sc, wi);
    awq_gemm6<<<dim3(8, 86), 256, 0, stream>>>(xi, wi, out);
}